// Round 1
// 838.111 us; speedup vs baseline: 1.1445x; 1.1445x over previous
//
#include <hip/hip_runtime.h>

typedef unsigned short u16;
typedef unsigned int u32;
typedef __attribute__((ext_vector_type(8))) __bf16 bf16x8;
typedef __attribute__((ext_vector_type(4))) float f32x4;
typedef __attribute__((ext_vector_type(8))) u16 u16x8;

// ---------- helpers ----------

__device__ __forceinline__ u16 f2bf(float f) {
    union { float f; u32 u; } v; v.f = f;
    u32 r = v.u + 0x7FFFu + ((v.u >> 16) & 1u);   // RNE
    return (u16)(r >> 16);
}

__device__ __forceinline__ void gload16(const void* g, void* l) {
    __builtin_amdgcn_global_load_lds(
        (const __attribute__((address_space(1))) u32*)g,
        (__attribute__((address_space(3))) u32*)l,
        16, 0, 0);
}

// ---------- fp32 -> bf16 elementwise (8 elems/thread) ----------
__global__ __launch_bounds__(256) void conv_bf16(
    const float* __restrict__ in, u16* __restrict__ out) {
    const size_t i = (size_t)blockIdx.x * 256 + threadIdx.x;
    const float4 a = ((const float4*)in)[i * 2];
    const float4 b = ((const float4*)in)[i * 2 + 1];
    u16x8 o;
    o[0] = f2bf(a.x); o[1] = f2bf(a.y); o[2] = f2bf(a.z); o[3] = f2bf(a.w);
    o[4] = f2bf(b.x); o[5] = f2bf(b.y); o[6] = f2bf(b.z); o[7] = f2bf(b.w);
    ((u16x8*)out)[i] = o;
}

// ---------- Ub[m,k] = bf16(U[m,k] * relu(S[k]+delta[k])) ----------
__global__ __launch_bounds__(64) void conv_scale(
    const float* __restrict__ U, const float* __restrict__ S,
    const float* __restrict__ D, u16* __restrict__ out) {
    const int m = blockIdx.y;
    const int k = (blockIdx.x * 64 + threadIdx.x) * 8;
    const size_t base = (size_t)m * 3072 + k;
    const float4 a = *(const float4*)&U[base];
    const float4 b = *(const float4*)&U[base + 4];
    const float4 s1 = *(const float4*)&S[k], s2 = *(const float4*)&S[k + 4];
    const float4 d1 = *(const float4*)&D[k], d2 = *(const float4*)&D[k + 4];
    u16x8 o;
    o[0] = f2bf(a.x * fmaxf(s1.x + d1.x, 0.f));
    o[1] = f2bf(a.y * fmaxf(s1.y + d1.y, 0.f));
    o[2] = f2bf(a.z * fmaxf(s1.z + d1.z, 0.f));
    o[3] = f2bf(a.w * fmaxf(s1.w + d1.w, 0.f));
    o[4] = f2bf(b.x * fmaxf(s2.x + d2.x, 0.f));
    o[5] = f2bf(b.y * fmaxf(s2.y + d2.y, 0.f));
    o[6] = f2bf(b.z * fmaxf(s2.z + d2.z, 0.f));
    o[7] = f2bf(b.w * fmaxf(s2.w + d2.w, 0.f));
    *(u16x8*)&out[base] = o;
}

// ---------- V^T -> bf16 (tiled transpose + convert) ----------
__global__ __launch_bounds__(256) void transpose_conv(
    const float* __restrict__ V, u16* __restrict__ Vt, int n) {
    __shared__ float tile[64][65];
    const int k0 = blockIdx.y * 64, j0 = blockIdx.x * 64;
    const int t = threadIdx.x;
    const int r = t >> 4, c4 = t & 15;
#pragma unroll
    for (int i = 0; i < 4; i++) {
        int row = i * 16 + r;
        const float4 v = *(const float4*)&V[(size_t)(k0 + row) * n + j0 + c4 * 4];
        tile[row][c4 * 4 + 0] = v.x;
        tile[row][c4 * 4 + 1] = v.y;
        tile[row][c4 * 4 + 2] = v.z;
        tile[row][c4 * 4 + 3] = v.w;
    }
    __syncthreads();
#pragma unroll
    for (int i = 0; i < 4; i++) {
        int row = i * 16 + r;  // local j
        ushort4 o;
        o.x = f2bf(tile[c4 * 4 + 0][row]);
        o.y = f2bf(tile[c4 * 4 + 1][row]);
        o.z = f2bf(tile[c4 * 4 + 2][row]);
        o.w = f2bf(tile[c4 * 4 + 3][row]);
        *(ushort4*)&Vt[(size_t)(j0 + row) * n + k0 + c4 * 4] = o;
    }
}

// ---------- bf16 NT GEMM (128x128 tile, m97-class): kept for the 3072^3 GEMM ----------
__global__ __launch_bounds__(256) void gemm_bt(
    const u16* __restrict__ A, const u16* __restrict__ B,
    float* __restrict__ C, int M, int N, int K) {
    __shared__ u16 As[128 * 64];
    __shared__ u16 Bs[128 * 64];
    const int t = threadIdx.x;
    const int m0 = blockIdx.y * 128, n0 = blockIdx.x * 128;
    const int wave = t >> 6, lane = t & 63;
    const int quad = lane >> 4, lrow = lane & 15;
    const int wm = (wave >> 1) * 64, wn = (wave & 1) * 64;
    const int gr = t >> 3;
    const int gc = (t & 7) ^ (gr & 7);
    const int c0 = (quad ^ (lrow & 7)) * 8;
    f32x4 acc[4][4] = {};

    const u16* Ag = A + (size_t)(m0 + gr) * K + gc * 8;
    const u16* Bg = B + (size_t)(n0 + gr) * K + gc * 8;

    for (int kb = 0; kb < K; kb += 64) {
#pragma unroll
        for (int i = 0; i < 4; i++) {
            gload16(Ag + (size_t)i * 32 * K + kb, (char*)As + i * 4096 + t * 16);
            gload16(Bg + (size_t)i * 32 * K + kb, (char*)Bs + i * 4096 + t * 16);
        }
        __syncthreads();
#pragma unroll
        for (int kk = 0; kk < 2; kk++) {
            const int co = c0 ^ (kk * 32);
            bf16x8 af[4], bfr[4];
#pragma unroll
            for (int mi = 0; mi < 4; mi++)
                af[mi] = *(const bf16x8*)&As[(wm + mi * 16 + lrow) * 64 + co];
#pragma unroll
            for (int ni = 0; ni < 4; ni++)
                bfr[ni] = *(const bf16x8*)&Bs[(wn + ni * 16 + lrow) * 64 + co];
#pragma unroll
            for (int mi = 0; mi < 4; mi++)
#pragma unroll
                for (int ni = 0; ni < 4; ni++)
                    acc[mi][ni] = __builtin_amdgcn_mfma_f32_16x16x32_bf16(
                        af[mi], bfr[ni], acc[mi][ni], 0, 0, 0);
        }
        __syncthreads();
    }
#pragma unroll
    for (int mi = 0; mi < 4; mi++) {
#pragma unroll
        for (int rr = 0; rr < 4; rr++) {
            int row = m0 + wm + mi * 16 + quad * 4 + rr;
            float* cp = C + (size_t)row * N + n0 + wn + lrow;
#pragma unroll
            for (int ni = 0; ni < 4; ni++) cp[ni * 16] = acc[mi][ni][rr];
        }
    }
}

// ---------- bf16 NT GEMM, 256x256 tile, 8-phase counted-vmcnt schedule ----------
// 512 threads = 8 waves (2M x 4N); each wave owns 128x64 output (8x4 16x16x32 frags).
// LDS per operand: [2 dbuf][2 K-half][256 rows][32 cols] bf16 (16 KiB slots, 128 KiB total).
// K-split halves give ordered consumption: phases 1-2 read k-half0, 3-4 read k-half1,
// so each phase stages exactly one half-tile into a slot whose readers finished a
// barrier earlier.  [256][32] layout is bank-even for ds_read_b128 (8 dwords/bank via
// row parity) -> no XOR swizzle needed.  Boundary s_waitcnt vmcnt(4) per K-tile keeps
// the 2 most recent half-tile prefetches in flight across the barrier (never drains
// to 0 in the main loop).  Requires M%256==0, N%256==0, K%64==0, K>=128, grid%8==0.
__global__ __launch_bounds__(512, 2) void gemm256(
    const u16* __restrict__ A, const u16* __restrict__ B,
    float* __restrict__ C, int M, int N, int K) {
    __shared__ u16 As[2][2][8192];
    __shared__ u16 Bs[2][2][8192];
    const int t = threadIdx.x;

    // XCD-aware swizzle (bijective since grid size % 8 == 0)
    const int nbx = gridDim.x;
    const int bid = blockIdx.y * nbx + blockIdx.x;
    const int cpx = (nbx * gridDim.y) >> 3;
    const int sid = (bid & 7) * cpx + (bid >> 3);
    const int m0 = (sid / nbx) * 256, n0 = (sid % nbx) * 256;

    const int lane = t & 63, quad = lane >> 4, lrow = lane & 15;
    const int wave = t >> 6, wr = wave >> 2, wc = wave & 3;

    // staging: thread t covers row (t>>2), 16B chunk (t&3) of a [128][32] half-issue;
    // two issues per half-tile (rows +0 and +128).
    const u16* Ag = A + (size_t)(m0 + (t >> 2)) * K + (t & 3) * 8;
    const u16* Bg = B + (size_t)(n0 + (t >> 2)) * K + (t & 3) * 8;
    const size_t row128 = (size_t)128 * K;

    // fragment read offsets (u16 index inside one [256][32] region)
    const int aoff = (wr * 128 + lrow) * 32 + quad * 8;
    const int boff = (wc * 64 + lrow) * 32 + quad * 8;

    f32x4 acc[8][4] = {};

#define STG(Gp, RG, kb, kh) do {                                              \
        gload16((Gp) + (kb) + (kh) * 32, (char*)(RG) + t * 16);               \
        gload16((Gp) + row128 + (kb) + (kh) * 32, (char*)(RG) + 8192 + t * 16); \
    } while (0)

    // prologue: tile0 both halves, tile1 k-half0; leave tile1-kh0 (4 loads) in flight
    STG(Ag, As[0][0], 0, 0);
    STG(Bg, Bs[0][0], 0, 0);
    STG(Ag, As[0][1], 0, 1);
    STG(Bg, Bs[0][1], 0, 1);
    STG(Ag, As[1][0], 64, 0);
    STG(Bg, Bs[1][0], 64, 0);
    asm volatile("s_waitcnt vmcnt(4)" ::: "memory");
    __builtin_amdgcn_s_barrier();

    const int NT = K >> 6;
    for (int tt = 0; tt < NT; ++tt) {
        const int b = tt & 1;
        const u16* A0 = As[b][0];
        const u16* A1 = As[b][1];
        const u16* B0 = Bs[b][0];
        const u16* B1 = Bs[b][1];
        bf16x8 bq[4], aq[4];

        // ---- phase 1: kk=0, mi 0-3 (8 ds_read) | stage A(t+1, kh1) ----
#pragma unroll
        for (int ni = 0; ni < 4; ni++) bq[ni] = *(const bf16x8*)&B0[boff + ni * 512];
#pragma unroll
        for (int mi = 0; mi < 4; mi++) aq[mi] = *(const bf16x8*)&A0[aoff + mi * 512];
        if (tt + 1 < NT) STG(Ag, As[b ^ 1][1], (tt + 1) * 64, 1);
        __builtin_amdgcn_s_barrier();
        asm volatile("s_waitcnt lgkmcnt(0)" ::: "memory");
        __builtin_amdgcn_sched_barrier(0);
        __builtin_amdgcn_s_setprio(1);
#pragma unroll
        for (int mi = 0; mi < 4; mi++)
#pragma unroll
            for (int ni = 0; ni < 4; ni++)
                acc[mi][ni] = __builtin_amdgcn_mfma_f32_16x16x32_bf16(
                    aq[mi], bq[ni], acc[mi][ni], 0, 0, 0);
        __builtin_amdgcn_s_setprio(0);
        __builtin_amdgcn_s_barrier();

        // ---- phase 2: kk=0, mi 4-7 (4 ds_read) | stage B(t+1, kh1) ----
#pragma unroll
        for (int mi = 0; mi < 4; mi++) aq[mi] = *(const bf16x8*)&A0[aoff + (mi + 4) * 512];
        if (tt + 1 < NT) STG(Bg, Bs[b ^ 1][1], (tt + 1) * 64, 1);
        __builtin_amdgcn_s_barrier();
        asm volatile("s_waitcnt lgkmcnt(0)" ::: "memory");
        __builtin_amdgcn_sched_barrier(0);
        __builtin_amdgcn_s_setprio(1);
#pragma unroll
        for (int mi = 0; mi < 4; mi++)
#pragma unroll
            for (int ni = 0; ni < 4; ni++)
                acc[mi + 4][ni] = __builtin_amdgcn_mfma_f32_16x16x32_bf16(
                    aq[mi], bq[ni], acc[mi + 4][ni], 0, 0, 0);
        __builtin_amdgcn_s_setprio(0);
        __builtin_amdgcn_s_barrier();

        // ---- phase 3: kk=1, mi 0-3 (8 ds_read) | stage A(t+2, kh0) ----
#pragma unroll
        for (int ni = 0; ni < 4; ni++) bq[ni] = *(const bf16x8*)&B1[boff + ni * 512];
#pragma unroll
        for (int mi = 0; mi < 4; mi++) aq[mi] = *(const bf16x8*)&A1[aoff + mi * 512];
        if (tt + 2 < NT) STG(Ag, As[b][0], (tt + 2) * 64, 0);
        __builtin_amdgcn_s_barrier();
        asm volatile("s_waitcnt lgkmcnt(0)" ::: "memory");
        __builtin_amdgcn_sched_barrier(0);
        __builtin_amdgcn_s_setprio(1);
#pragma unroll
        for (int mi = 0; mi < 4; mi++)
#pragma unroll
            for (int ni = 0; ni < 4; ni++)
                acc[mi][ni] = __builtin_amdgcn_mfma_f32_16x16x32_bf16(
                    aq[mi], bq[ni], acc[mi][ni], 0, 0, 0);
        __builtin_amdgcn_s_setprio(0);
        __builtin_amdgcn_s_barrier();

        // ---- phase 4: kk=1, mi 4-7 (4 ds_read) | stage B(t+2, kh0) | boundary vmcnt ----
#pragma unroll
        for (int mi = 0; mi < 4; mi++) aq[mi] = *(const bf16x8*)&A1[aoff + (mi + 4) * 512];
        if (tt + 2 < NT) STG(Bg, Bs[b][0], (tt + 2) * 64, 0);
        __builtin_amdgcn_s_barrier();
        asm volatile("s_waitcnt lgkmcnt(0)" ::: "memory");
        __builtin_amdgcn_sched_barrier(0);
        __builtin_amdgcn_s_setprio(1);
#pragma unroll
        for (int mi = 0; mi < 4; mi++)
#pragma unroll
            for (int ni = 0; ni < 4; ni++)
                acc[mi + 4][ni] = __builtin_amdgcn_mfma_f32_16x16x32_bf16(
                    aq[mi], bq[ni], acc[mi + 4][ni], 0, 0, 0);
        __builtin_amdgcn_s_setprio(0);
        if (tt + 2 < NT)
            asm volatile("s_waitcnt vmcnt(4)" ::: "memory");   // next tile complete; 2 half-tiles stay in flight
        else if (tt + 1 < NT)
            asm volatile("s_waitcnt vmcnt(0)" ::: "memory");   // tail: drain last tile's kh1
        __builtin_amdgcn_s_barrier();
    }
#undef STG

    // epilogue: C/D layout col=lane&15, row=quad*4+reg
#pragma unroll
    for (int mi = 0; mi < 8; mi++) {
#pragma unroll
        for (int rr = 0; rr < 4; rr++) {
            const int row = m0 + wr * 128 + mi * 16 + quad * 4 + rr;
            float* cp = C + (size_t)row * N + n0 + wc * 64 + lrow;
#pragma unroll
            for (int ni = 0; ni < 4; ni++) cp[ni * 16] = acc[mi][ni][rr];
        }
    }
}

// ---------- Kron apply: WtT[o,:] = bf16( (Q1 (x) Q2 (x) Q3) @ W[o,:] ) ----------
__global__ __launch_bounds__(256) void kron_apply(
    const float* __restrict__ W, const float* __restrict__ Q1,
    const float* __restrict__ Q2, const float* __restrict__ Q3,
    u16* __restrict__ WtT) {
    __shared__ float T0[3072], T1[3072];
    __shared__ float Q1s[256], Q2s[256], Q3s[144];
    const int o = blockIdx.x, t = threadIdx.x;
#pragma unroll
    for (int i = 0; i < 12; i++) T0[t + i * 256] = W[(size_t)o * 3072 + t + i * 256];
    Q1s[t] = Q1[t];
    Q2s[t] = Q2[t];
    if (t < 144) Q3s[t] = Q3[t];
    __syncthreads();
#pragma unroll
    for (int i = 0; i < 12; i++) {
        int e = t + i * 256;
        int d1 = e / 192, rem = e % 192;
        float s = 0.f;
#pragma unroll
        for (int j1 = 0; j1 < 16; j1++) s += Q1s[d1 * 16 + j1] * T0[j1 * 192 + rem];
        T1[e] = s;
    }
    __syncthreads();
#pragma unroll
    for (int i = 0; i < 12; i++) {
        int e = t + i * 256;
        int j3 = e % 12, d2 = (e / 12) & 15, d1 = e / 192;
        float s = 0.f;
#pragma unroll
        for (int j2 = 0; j2 < 16; j2++) s += Q2s[d2 * 16 + j2] * T1[d1 * 192 + j2 * 12 + j3];
        T0[e] = s;
    }
    __syncthreads();
#pragma unroll
    for (int i = 0; i < 12; i++) {
        int e = t + i * 256;
        int d3 = e % 12, b = e - d3;
        float s = 0.f;
#pragma unroll
        for (int j3 = 0; j3 < 12; j3++) s += Q3s[d3 * 12 + j3] * T0[b + j3];
        WtT[(size_t)o * 3072 + e] = f2bf(s);
    }
}

// ---------- launch ----------
extern "C" void kernel_launch(void* const* d_in, const int* in_sizes, int n_in,
                              void* d_out, int out_size, void* d_ws, size_t ws_size,
                              hipStream_t stream) {
    const float* x   = (const float*)d_in[0];  // [4,4096,3072]
    const float* U   = (const float*)d_in[1];  // [3072,3072]
    const float* S   = (const float*)d_in[2];  // [3072]
    const float* V   = (const float*)d_in[3];  // [3072,3072]
    const float* dl  = (const float*)d_in[4];  // [3072]
    const float* Q1  = (const float*)d_in[5];  // [16,16]
    const float* Q2  = (const float*)d_in[6];  // [16,16]
    const float* Q3  = (const float*)d_in[7];  // [12,12]
    float* out = (float*)d_out;                // [16384,3072]

    char* ws = (char*)d_ws;
    u16*   xb  = (u16*)ws;                                    // 100,663,296 B
    u16*   Ub  = (u16*)(ws + 100663296);                      //  18,874,368 B
    u16*   Vt  = (u16*)(ws + 100663296 + 18874368);           //  18,874,368 B
    float* W   = (float*)(ws + 100663296 + 2 * 18874368);     //  37,748,736 B
    u16*   WtT = Ub;  // alias: Ub is dead once gemm1 completes

    // 1) xb = bf16(x)
    hipLaunchKernelGGL(conv_bf16, dim3(24576), dim3(256), 0, stream, x, xb);
    // 2) Ub = bf16(U * relu(S+delta))
    hipLaunchKernelGGL(conv_scale, dim3(6, 3072), dim3(64), 0, stream, U, S, dl, Ub);
    // 3) Vt = bf16(V^T)
    hipLaunchKernelGGL(transpose_conv, dim3(48, 48), dim3(256), 0, stream, V, Vt, 3072);
    // 4) W = Ub @ Vt^T  (= (U*Sp) @ V)   -- 128^2 kernel (144 blocks at 256^2 would underfill)
    hipLaunchKernelGGL(gemm_bt, dim3(24, 24), dim3(256), 0, stream,
                       Ub, Vt, W, 3072, 3072, 3072);
    // 5) WtT[o,:] = bf16(kron(Q1,Q2,Q3) @ W[o,:])
    hipLaunchKernelGGL(kron_apply, dim3(3072), dim3(256), 0, stream, W, Q1, Q2, Q3, WtT);
    // 6) out = xb @ WtT^T  (= x @ W_t)   -- 256^2 8-phase kernel, 768 blocks
    hipLaunchKernelGGL(gemm256, dim3(12, 64), dim3(512), 0, stream,
                       xb, WtT, out, 16384, 3072, 3072);
}